// Round 1
// baseline (2869.627 us; speedup 1.0000x reference)
//
#include <hip/hip_runtime.h>

#define D 128
#define D4 32   // D / 4 (float4 groups)

// ---------------------------------------------------------------------------
// GEMM: support[n][c] = b[c] + sum_k x[n][k] * W[k][c]
// Block = 256 threads, tile = 32 nodes x 128 cols, thread = 4 nodes x 4 cols.
// LDS: W full (64 KB) + x tile (16 KB) = 80 KB -> 2 blocks/CU.
// ---------------------------------------------------------------------------
__global__ __launch_bounds__(256) void gcn_gemm_kernel(
    const float* __restrict__ x, const float* __restrict__ W,
    const float* __restrict__ b, float* __restrict__ sup, int n_nodes) {
  __shared__ float Ws[D * D];    // 64 KB
  __shared__ float xs[32 * D];   // 16 KB
  const int t = threadIdx.x;
  const int node0 = blockIdx.x * 32;

  // Stage W (128x128 fp32) into LDS, float4-coalesced.
  const float4* W4 = (const float4*)W;
  float4* Ws4 = (float4*)Ws;
#pragma unroll
  for (int i = 0; i < 16; ++i) Ws4[t + 256 * i] = W4[t + 256 * i];

  // Stage x tile (32 x 128) into LDS, float4-coalesced, row-guarded.
  const float4* x4 = (const float4*)x;
  float4* xs4 = (float4*)xs;
#pragma unroll
  for (int i = 0; i < 4; ++i) {
    int l = t + 256 * i;   // 0..1023
    int r = l >> 5;        // node within tile
    int k4 = l & 31;       // float4 index within row
    int node = node0 + r;
    float4 v = make_float4(0.f, 0.f, 0.f, 0.f);
    if (node < n_nodes) v = x4[(size_t)node * D4 + k4];
    xs4[l] = v;
  }
  __syncthreads();

  const int cg = t & 31;        // column float4 group (cols cg*4..cg*4+3)
  const int r0 = (t >> 5) * 4;  // first of 4 nodes

  float4 bv = ((const float4*)b)[cg];
  float4 acc[4];
#pragma unroll
  for (int r = 0; r < 4; ++r) acc[r] = bv;

  for (int k = 0; k < D; k += 4) {
    float4 wv[4];
#pragma unroll
    for (int j = 0; j < 4; ++j) wv[j] = Ws4[(k + j) * D4 + cg];
    float4 xv[4];
#pragma unroll
    for (int r = 0; r < 4; ++r) xv[r] = xs4[(r0 + r) * D4 + (k >> 2)];
#pragma unroll
    for (int r = 0; r < 4; ++r) {
      float xr;
      xr = xv[r].x;
      acc[r].x += xr * wv[0].x; acc[r].y += xr * wv[0].y;
      acc[r].z += xr * wv[0].z; acc[r].w += xr * wv[0].w;
      xr = xv[r].y;
      acc[r].x += xr * wv[1].x; acc[r].y += xr * wv[1].y;
      acc[r].z += xr * wv[1].z; acc[r].w += xr * wv[1].w;
      xr = xv[r].z;
      acc[r].x += xr * wv[2].x; acc[r].y += xr * wv[2].y;
      acc[r].z += xr * wv[2].z; acc[r].w += xr * wv[2].w;
      xr = xv[r].w;
      acc[r].x += xr * wv[3].x; acc[r].y += xr * wv[3].y;
      acc[r].z += xr * wv[3].z; acc[r].w += xr * wv[3].w;
    }
  }

  float4* sup4 = (float4*)sup;
#pragma unroll
  for (int r = 0; r < 4; ++r) {
    int node = node0 + r0 + r;
    if (node < n_nodes) sup4[(size_t)node * D4 + cg] = acc[r];
  }
}

// ---------------------------------------------------------------------------
// Scatter: out[rows[e]] += vals[e] * support[cols[e]]
// 32 lanes per edge; each lane handles one float4 (4 features) -> 4 HW f32
// atomics. Gather of support[col] is 512 B contiguous per edge.
// ---------------------------------------------------------------------------
__global__ __launch_bounds__(256) void gcn_scatter_kernel(
    const float* __restrict__ sup, const int* __restrict__ rows,
    const int* __restrict__ cols, const float* __restrict__ vals,
    float* __restrict__ out, int n_edges) {
  int tid = blockIdx.x * 256 + threadIdx.x;
  int e = tid >> 5;
  int lane = tid & 31;
  if (e >= n_edges) return;

  int col = cols[e];
  int row = rows[e];
  float val = vals[e];

  float4 s = ((const float4*)sup)[(size_t)col * D4 + lane];
  float* dst = out + (size_t)row * D + lane * 4;
  unsafeAtomicAdd(dst + 0, s.x * val);
  unsafeAtomicAdd(dst + 1, s.y * val);
  unsafeAtomicAdd(dst + 2, s.z * val);
  unsafeAtomicAdd(dst + 3, s.w * val);
}

extern "C" void kernel_launch(void* const* d_in, const int* in_sizes, int n_in,
                              void* d_out, int out_size, void* d_ws, size_t ws_size,
                              hipStream_t stream) {
  const float* x    = (const float*)d_in[0];
  const int*   rows = (const int*)d_in[1];
  const int*   cols = (const int*)d_in[2];
  const float* vals = (const float*)d_in[3];
  const float* W    = (const float*)d_in[4];
  const float* b    = (const float*)d_in[5];
  float* out = (float*)d_out;
  float* sup = (float*)d_ws;  // n_nodes * 128 fp32 = 51.2 MB scratch

  int n_nodes = in_sizes[0] / D;
  int n_edges = in_sizes[1];

  // Harness poisons d_out with 0xAA before every timed launch -> zero it.
  hipMemsetAsync(d_out, 0, (size_t)out_size * sizeof(float), stream);

  gcn_gemm_kernel<<<dim3((n_nodes + 31) / 32), dim3(256), 0, stream>>>(
      x, W, b, sup, n_nodes);

  int total_lanes = n_edges * 32;
  gcn_scatter_kernel<<<dim3((total_lanes + 255) / 256), dim3(256), 0, stream>>>(
      sup, rows, cols, vals, out, n_edges);
}

// Round 2
// 451.299 us; speedup vs baseline: 6.3586x; 6.3586x over previous
//
#include <hip/hip_runtime.h>

#define D 128
#define D4 32        // D/4 float4 groups
#define NCHUNK_MAX 512

__device__ inline unsigned short f2bf(float f) {
  unsigned u = __float_as_uint(f);
  u += 0x7fffu + ((u >> 16) & 1u);   // round-to-nearest-even
  return (unsigned short)(u >> 16);
}

// ---------------------------------------------------------------------------
// GEMM: support[n][c] = b[c] + sum_k x[n][k]*W[k][c], output stored as bf16.
// ---------------------------------------------------------------------------
__global__ __launch_bounds__(256) void gcn_gemm_kernel(
    const float* __restrict__ x, const float* __restrict__ W,
    const float* __restrict__ b, unsigned short* __restrict__ sup, int n_nodes) {
  __shared__ float Ws[D * D];    // 64 KB
  __shared__ float xs[32 * D];   // 16 KB
  const int t = threadIdx.x;
  const int node0 = blockIdx.x * 32;

  const float4* W4 = (const float4*)W;
  float4* Ws4 = (float4*)Ws;
#pragma unroll
  for (int i = 0; i < 16; ++i) Ws4[t + 256 * i] = W4[t + 256 * i];

  const float4* x4 = (const float4*)x;
  float4* xs4 = (float4*)xs;
#pragma unroll
  for (int i = 0; i < 4; ++i) {
    int l = t + 256 * i;
    int r = l >> 5, k4 = l & 31;
    int node = node0 + r;
    float4 v = make_float4(0.f, 0.f, 0.f, 0.f);
    if (node < n_nodes) v = x4[(size_t)node * D4 + k4];
    xs4[l] = v;
  }
  __syncthreads();

  const int cg = t & 31;
  const int r0 = (t >> 5) * 4;

  float4 bv = ((const float4*)b)[cg];
  float4 acc[4];
#pragma unroll
  for (int r = 0; r < 4; ++r) acc[r] = bv;

  for (int k = 0; k < D; k += 4) {
    float4 wv[4];
#pragma unroll
    for (int j = 0; j < 4; ++j) wv[j] = Ws4[(k + j) * D4 + cg];
    float4 xv[4];
#pragma unroll
    for (int r = 0; r < 4; ++r) xv[r] = xs4[(r0 + r) * D4 + (k >> 2)];
#pragma unroll
    for (int r = 0; r < 4; ++r) {
      float xr;
      xr = xv[r].x;
      acc[r].x += xr * wv[0].x; acc[r].y += xr * wv[0].y;
      acc[r].z += xr * wv[0].z; acc[r].w += xr * wv[0].w;
      xr = xv[r].y;
      acc[r].x += xr * wv[1].x; acc[r].y += xr * wv[1].y;
      acc[r].z += xr * wv[1].z; acc[r].w += xr * wv[1].w;
      xr = xv[r].z;
      acc[r].x += xr * wv[2].x; acc[r].y += xr * wv[2].y;
      acc[r].z += xr * wv[2].z; acc[r].w += xr * wv[2].w;
      xr = xv[r].w;
      acc[r].x += xr * wv[3].x; acc[r].y += xr * wv[3].y;
      acc[r].z += xr * wv[3].z; acc[r].w += xr * wv[3].w;
    }
  }

  ushort4* sup4 = (ushort4*)sup;   // row = 32 ushort4 slots (128 bf16)
#pragma unroll
  for (int r = 0; r < 4; ++r) {
    int node = node0 + r0 + r;
    if (node < n_nodes) {
      ushort4 o;
      o.x = f2bf(acc[r].x); o.y = f2bf(acc[r].y);
      o.z = f2bf(acc[r].z); o.w = f2bf(acc[r].w);
      sup4[(size_t)node * D4 + cg] = o;
    }
  }
}

// ---------------------------------------------------------------------------
// CSR build: histogram -> 3-kernel exclusive scan -> permuted (col,val) pairs
// ---------------------------------------------------------------------------
__global__ __launch_bounds__(256) void hist_kernel(
    const int* __restrict__ rows, int* __restrict__ cnt, int n_edges) {
  int e = blockIdx.x * 256 + threadIdx.x;
  if (e < n_edges) atomicAdd(&cnt[rows[e]], 1);
}

__global__ __launch_bounds__(256) void scan1_kernel(
    const int* __restrict__ cnt, int* __restrict__ partial, int n) {
  __shared__ int s[256];
  int t = threadIdx.x;
  int i = blockIdx.x * 256 + t;
  s[t] = (i < n) ? cnt[i] : 0;
  __syncthreads();
#pragma unroll
  for (int d = 128; d > 0; d >>= 1) {
    if (t < d) s[t] += s[t + d];
    __syncthreads();
  }
  if (t == 0) partial[blockIdx.x] = s[0];
}

__global__ __launch_bounds__(512) void scan2_kernel(
    const int* __restrict__ partial, int* __restrict__ chunk_off, int nchunk) {
  __shared__ int s[NCHUNK_MAX];
  int t = threadIdx.x;
  s[t] = (t < nchunk) ? partial[t] : 0;
  __syncthreads();
  for (int d = 1; d < NCHUNK_MAX; d <<= 1) {
    int v = (t >= d) ? s[t - d] : 0;
    __syncthreads();
    s[t] += v;
    __syncthreads();
  }
  if (t < nchunk) chunk_off[t] = (t == 0) ? 0 : s[t - 1];
}

__global__ __launch_bounds__(256) void scan3_kernel(
    const int* __restrict__ cnt, const int* __restrict__ chunk_off,
    int* __restrict__ row_start, int* __restrict__ cursor,
    int n, int n_edges) {
  __shared__ int s[256];
  int t = threadIdx.x;
  int i = blockIdx.x * 256 + t;
  s[t] = (i < n) ? cnt[i] : 0;
  __syncthreads();
  // inclusive Hillis-Steele
  for (int d = 1; d < 256; d <<= 1) {
    int v = (t >= d) ? s[t - d] : 0;
    __syncthreads();
    s[t] += v;
    __syncthreads();
  }
  if (i < n) {
    int excl = chunk_off[blockIdx.x] + ((t == 0) ? 0 : s[t - 1]);
    row_start[i] = excl;
    cursor[i] = excl;
  }
  if (blockIdx.x == 0 && t == 0) row_start[n] = n_edges;
}

__global__ __launch_bounds__(256) void build_kernel(
    const int* __restrict__ rows, const int* __restrict__ cols,
    const float* __restrict__ vals, int* __restrict__ cursor,
    int2* __restrict__ pairs, int n_edges) {
  int e = blockIdx.x * 256 + threadIdx.x;
  if (e >= n_edges) return;
  int row = rows[e];
  int pos = atomicAdd(&cursor[row], 1);
  pairs[pos] = make_int2(cols[e], __float_as_int(vals[e]));
}

// ---------------------------------------------------------------------------
// Gather: 32 threads per row, each owning 4 features (bf16x4 = 8 B loads).
// out[r] = sum_e val_e * support[col_e]   (fp32 accumulate, no atomics)
// ---------------------------------------------------------------------------
__global__ __launch_bounds__(256) void gather_kernel(
    const unsigned short* __restrict__ sup, const int* __restrict__ row_start,
    const int2* __restrict__ pairs, float* __restrict__ out, int n_nodes) {
  int tid = blockIdx.x * 256 + threadIdx.x;
  int g = tid >> 5;       // row
  int lane = tid & 31;    // feature group
  if (g >= n_nodes) return;

  int s = row_start[g];
  int e = row_start[g + 1];
  const uint2* supv = (const uint2*)sup;  // 4 bf16 per uint2, 32 per row

  float4 acc = make_float4(0.f, 0.f, 0.f, 0.f);
  for (int i = s; i < e; ++i) {
    int2 p = pairs[i];                 // broadcast across the 32 lanes
    float val = __int_as_float(p.y);
    uint2 sv = supv[(size_t)p.x * D4 + lane];
    float f0 = __uint_as_float(sv.x << 16);
    float f1 = __uint_as_float(sv.x & 0xffff0000u);
    float f2 = __uint_as_float(sv.y << 16);
    float f3 = __uint_as_float(sv.y & 0xffff0000u);
    acc.x += val * f0;
    acc.y += val * f1;
    acc.z += val * f2;
    acc.w += val * f3;
  }
  ((float4*)out)[(size_t)g * D4 + lane] = acc;
}

extern "C" void kernel_launch(void* const* d_in, const int* in_sizes, int n_in,
                              void* d_out, int out_size, void* d_ws, size_t ws_size,
                              hipStream_t stream) {
  const float* x    = (const float*)d_in[0];
  const int*   rows = (const int*)d_in[1];
  const int*   cols = (const int*)d_in[2];
  const float* vals = (const float*)d_in[3];
  const float* W    = (const float*)d_in[4];
  const float* b    = (const float*)d_in[5];
  float* out = (float*)d_out;

  int n_nodes = in_sizes[0] / D;
  int n_edges = in_sizes[1];

  // workspace layout (total ~39.6 MB, proven >= 51.2 MB available)
  char* ws = (char*)d_ws;
  unsigned short* sup = (unsigned short*)(ws);                 // 25,600,000 B
  int2* pairs         = (int2*)(ws + 25600000);                // 12,800,000 B
  int* cnt            = (int*)(ws + 38400000);                 //    400,000 B
  int* row_start      = (int*)(ws + 38800000);                 //    400,032 B
  int* cursor         = (int*)(ws + 39200032);                 //    400,000 B
  int* partial        = (int*)(ws + 39600032);                 //      2,048 B
  int* chunk_off      = (int*)(ws + 39602080);                 //      2,048 B

  int nchunk = (n_nodes + 255) / 256;

  hipMemsetAsync(cnt, 0, (size_t)n_nodes * sizeof(int), stream);

  gcn_gemm_kernel<<<dim3((n_nodes + 31) / 32), dim3(256), 0, stream>>>(
      x, W, b, sup, n_nodes);

  int eblocks = (n_edges + 255) / 256;
  hist_kernel<<<dim3(eblocks), dim3(256), 0, stream>>>(rows, cnt, n_edges);
  scan1_kernel<<<dim3(nchunk), dim3(256), 0, stream>>>(cnt, partial, n_nodes);
  scan2_kernel<<<dim3(1), dim3(NCHUNK_MAX), 0, stream>>>(partial, chunk_off, nchunk);
  scan3_kernel<<<dim3(nchunk), dim3(256), 0, stream>>>(
      cnt, chunk_off, row_start, cursor, n_nodes, n_edges);
  build_kernel<<<dim3(eblocks), dim3(256), 0, stream>>>(
      rows, cols, vals, cursor, pairs, n_edges);

  int gblocks = ((n_nodes * 32) + 255) / 256;
  gather_kernel<<<dim3(gblocks), dim3(256), 0, stream>>>(
      sup, row_start, pairs, out, n_nodes);
}

// Round 3
// 391.185 us; speedup vs baseline: 7.3357x; 1.1537x over previous
//
#include <hip/hip_runtime.h>

#define D 128
#define D4 32        // D/4 float4 groups
#define NB_MAX 512   // max coarse buckets (n_nodes/256 = 391 here)
#define CH 2048      // edges per partition block

__device__ inline unsigned short f2bf(float f) {
  unsigned u = __float_as_uint(f);
  u += 0x7fffu + ((u >> 16) & 1u);   // round-to-nearest-even
  return (unsigned short)(u >> 16);
}

// ---------------------------------------------------------------------------
// GEMM: support[n][c] = b[c] + sum_k x[n][k]*W[k][c], output stored as bf16.
// ---------------------------------------------------------------------------
__global__ __launch_bounds__(256) void gcn_gemm_kernel(
    const float* __restrict__ x, const float* __restrict__ W,
    const float* __restrict__ b, unsigned short* __restrict__ sup, int n_nodes) {
  __shared__ float Ws[D * D];    // 64 KB
  __shared__ float xs[32 * D];   // 16 KB
  const int t = threadIdx.x;
  const int node0 = blockIdx.x * 32;

  const float4* W4 = (const float4*)W;
  float4* Ws4 = (float4*)Ws;
#pragma unroll
  for (int i = 0; i < 16; ++i) Ws4[t + 256 * i] = W4[t + 256 * i];

  const float4* x4 = (const float4*)x;
  float4* xs4 = (float4*)xs;
#pragma unroll
  for (int i = 0; i < 4; ++i) {
    int l = t + 256 * i;
    int r = l >> 5, k4 = l & 31;
    int node = node0 + r;
    float4 v = make_float4(0.f, 0.f, 0.f, 0.f);
    if (node < n_nodes) v = x4[(size_t)node * D4 + k4];
    xs4[l] = v;
  }
  __syncthreads();

  const int cg = t & 31;
  const int r0 = (t >> 5) * 4;

  float4 bv = ((const float4*)b)[cg];
  float4 acc[4];
#pragma unroll
  for (int r = 0; r < 4; ++r) acc[r] = bv;

  for (int k = 0; k < D; k += 4) {
    float4 wv[4];
#pragma unroll
    for (int j = 0; j < 4; ++j) wv[j] = Ws4[(k + j) * D4 + cg];
    float4 xv[4];
#pragma unroll
    for (int r = 0; r < 4; ++r) xv[r] = xs4[(r0 + r) * D4 + (k >> 2)];
#pragma unroll
    for (int r = 0; r < 4; ++r) {
      float xr;
      xr = xv[r].x;
      acc[r].x += xr * wv[0].x; acc[r].y += xr * wv[0].y;
      acc[r].z += xr * wv[0].z; acc[r].w += xr * wv[0].w;
      xr = xv[r].y;
      acc[r].x += xr * wv[1].x; acc[r].y += xr * wv[1].y;
      acc[r].z += xr * wv[1].z; acc[r].w += xr * wv[1].w;
      xr = xv[r].z;
      acc[r].x += xr * wv[2].x; acc[r].y += xr * wv[2].y;
      acc[r].z += xr * wv[2].z; acc[r].w += xr * wv[2].w;
      xr = xv[r].w;
      acc[r].x += xr * wv[3].x; acc[r].y += xr * wv[3].y;
      acc[r].z += xr * wv[3].z; acc[r].w += xr * wv[3].w;
    }
  }

  ushort4* sup4 = (ushort4*)sup;
#pragma unroll
  for (int r = 0; r < 4; ++r) {
    int node = node0 + r0 + r;
    if (node < n_nodes) {
      ushort4 o;
      o.x = f2bf(acc[r].x); o.y = f2bf(acc[r].y);
      o.z = f2bf(acc[r].z); o.w = f2bf(acc[r].w);
      sup4[(size_t)node * D4 + cg] = o;
    }
  }
}

// ---------------------------------------------------------------------------
// Pass A: coarse bucket histogram (bucket = row >> 8), LDS-privatized.
// ---------------------------------------------------------------------------
__global__ __launch_bounds__(256) void bucket_hist_kernel(
    const int* __restrict__ rows, int* __restrict__ bucket_cnt, int n_edges) {
  __shared__ int h[NB_MAX];
  int t = threadIdx.x;
  for (int i = t; i < NB_MAX; i += 256) h[i] = 0;
  __syncthreads();
  int lo = blockIdx.x * 4096;
  int hi = min(lo + 4096, n_edges);
  for (int i = lo + t; i < hi; i += 256) atomicAdd(&h[rows[i] >> 8], 1);
  __syncthreads();
  for (int i = t; i < NB_MAX; i += 256)
    if (h[i]) atomicAdd(&bucket_cnt[i], h[i]);
}

// ---------------------------------------------------------------------------
// Pass B: scan bucket counts -> bucket_off, init bucket_cursor. One block.
// ---------------------------------------------------------------------------
__global__ __launch_bounds__(512) void bucket_scan_kernel(
    const int* __restrict__ bucket_cnt, int* __restrict__ bucket_off,
    int* __restrict__ bucket_cursor, int nb) {
  __shared__ int s[512];
  int t = threadIdx.x;
  s[t] = (t < nb) ? bucket_cnt[t] : 0;
  __syncthreads();
  for (int d = 1; d < 512; d <<= 1) {
    int v = (t >= d) ? s[t - d] : 0;
    __syncthreads();
    s[t] += v;
    __syncthreads();
  }
  int excl = (t == 0) ? 0 : s[t - 1];
  if (t < nb) { bucket_off[t] = excl; bucket_cursor[t] = excl; }
  if (t == nb) bucket_off[t] = s[nb - 1];   // total = n_edges
}

// ---------------------------------------------------------------------------
// Pass C: partition edges into bucket-contiguous regions of tmp.
// Per-block LDS histogram -> one global atomic per (block,bucket) -> writes
// land in ~10-edge contiguous runs (near-full-line utilization).
// tmp element: { meta = (lrow<<17)|col , val }
// ---------------------------------------------------------------------------
__global__ __launch_bounds__(256) void partition_kernel(
    const int* __restrict__ rows, const int* __restrict__ cols,
    const float* __restrict__ vals, int* __restrict__ bucket_cursor,
    int2* __restrict__ tmp, int n_edges) {
  __shared__ int h[NB_MAX];
  __shared__ int base_s[NB_MAX];
  int t = threadIdx.x;
  for (int i = t; i < NB_MAX; i += 256) h[i] = 0;
  __syncthreads();
  int lo = blockIdx.x * CH;
  int hi = min(lo + CH, n_edges);
  for (int i = lo + t; i < hi; i += 256) atomicAdd(&h[rows[i] >> 8], 1);
  __syncthreads();
  for (int i = t; i < NB_MAX; i += 256) {
    int c = h[i];
    base_s[i] = c ? atomicAdd(&bucket_cursor[i], c) : 0;
    h[i] = 0;   // reuse as local cursor
  }
  __syncthreads();
  for (int i = lo + t; i < hi; i += 256) {
    int r = rows[i];
    int bkt = r >> 8;
    int l = atomicAdd(&h[bkt], 1);
    int pos = base_s[bkt] + l;
    tmp[pos] = make_int2(((r & 255) << 17) | cols[i], __float_as_int(vals[i]));
  }
}

// ---------------------------------------------------------------------------
// Pass D: per-bucket counting sort (256 local rows) -> final CSR pairs +
// row_start. One block per bucket; scatter confined to the bucket's ~32 KB.
// ---------------------------------------------------------------------------
__global__ __launch_bounds__(256) void bucket_sort_kernel(
    const int2* __restrict__ tmp, const int* __restrict__ bucket_off,
    int2* __restrict__ pairs, int* __restrict__ row_start,
    int n_nodes, int n_edges) {
  __shared__ int cnt[256];
  __shared__ int loff[256];
  __shared__ int s[256];
  int b = blockIdx.x, t = threadIdx.x;
  cnt[t] = 0;
  __syncthreads();
  int lo = bucket_off[b], hi = bucket_off[b + 1];
  for (int i = lo + t; i < hi; i += 256) {
    int lr = ((unsigned)tmp[i].x) >> 17;
    atomicAdd(&cnt[lr], 1);
  }
  __syncthreads();
  s[t] = cnt[t];
  __syncthreads();
  for (int d = 1; d < 256; d <<= 1) {
    int v = (t >= d) ? s[t - d] : 0;
    __syncthreads();
    s[t] += v;
    __syncthreads();
  }
  int excl = (t == 0) ? 0 : s[t - 1];
  loff[t] = excl;
  cnt[t] = 0;   // reuse as per-row cursor
  int g = (b << 8) + t;
  if (g < n_nodes) row_start[g] = lo + excl;
  if (b == 0 && t == 0) row_start[n_nodes] = n_edges;
  __syncthreads();
  for (int i = lo + t; i < hi; i += 256) {
    int2 p = tmp[i];
    int lr = ((unsigned)p.x) >> 17;
    int l = atomicAdd(&cnt[lr], 1);
    pairs[lo + loff[lr] + l] = make_int2(p.x & 0x1FFFF, p.y);
  }
}

// ---------------------------------------------------------------------------
// Gather: one wave (64 lanes) per row, 2 bf16 features per lane.
// out[r] = sum_e val_e * support[col_e]   (fp32 accumulate, no atomics)
// ---------------------------------------------------------------------------
__global__ __launch_bounds__(256) void gather_kernel(
    const unsigned* __restrict__ sup, const int* __restrict__ row_start,
    const int2* __restrict__ pairs, float* __restrict__ out, int n_nodes) {
  int tid = blockIdx.x * 256 + threadIdx.x;
  int g = tid >> 6;      // row
  int lane = tid & 63;   // uint index (2 bf16 features)
  if (g >= n_nodes) return;

  int s = row_start[g];
  int e = row_start[g + 1];
  float2 acc = make_float2(0.f, 0.f);
  for (int i = s; i < e; ++i) {
    int2 p = pairs[i];   // wave-uniform broadcast
    float val = __int_as_float(p.y);
    unsigned sv = sup[((size_t)p.x << 6) + lane];
    acc.x += val * __uint_as_float(sv << 16);
    acc.y += val * __uint_as_float(sv & 0xffff0000u);
  }
  ((float2*)out)[((size_t)g << 6) + lane] = acc;
}

extern "C" void kernel_launch(void* const* d_in, const int* in_sizes, int n_in,
                              void* d_out, int out_size, void* d_ws, size_t ws_size,
                              hipStream_t stream) {
  const float* x    = (const float*)d_in[0];
  const int*   rows = (const int*)d_in[1];
  const int*   cols = (const int*)d_in[2];
  const float* vals = (const float*)d_in[3];
  const float* W    = (const float*)d_in[4];
  const float* b    = (const float*)d_in[5];
  float* out = (float*)d_out;

  int n_nodes = in_sizes[0] / D;
  int n_edges = in_sizes[1];
  int nb = (n_nodes + 255) >> 8;   // 391 coarse buckets

  // workspace layout (~38.8 MB):
  //   [0, 25.6M)        sup (bf16, written by GEMM)  -- tmp aliases [0,12.8M)
  //   [25.6M, 38.4M)    final CSR pairs
  //   [38.4M, ...)      row_start (N+1), bucket arrays
  char* ws = (char*)d_ws;
  unsigned short* sup = (unsigned short*)(ws);
  int2* tmp           = (int2*)(ws);                 // dead once GEMM runs
  int2* pairs         = (int2*)(ws + 25600000);
  int* row_start      = (int*)(ws + 38400000);       // 400,004 B
  int* bucket_cnt     = (int*)(ws + 38800016);       // 1,568 B
  int* bucket_off     = (int*)(ws + 38801600);       // 1,568 B
  int* bucket_cursor  = (int*)(ws + 38803168);       // 1,568 B

  hipMemsetAsync(bucket_cnt, 0, (size_t)nb * sizeof(int), stream);

  int ablocks = (n_edges + 4095) / 4096;
  bucket_hist_kernel<<<dim3(ablocks), dim3(256), 0, stream>>>(
      rows, bucket_cnt, n_edges);
  bucket_scan_kernel<<<dim3(1), dim3(512), 0, stream>>>(
      bucket_cnt, bucket_off, bucket_cursor, nb);
  int cblocks = (n_edges + CH - 1) / CH;
  partition_kernel<<<dim3(cblocks), dim3(256), 0, stream>>>(
      rows, cols, vals, bucket_cursor, tmp, n_edges);
  bucket_sort_kernel<<<dim3(nb), dim3(256), 0, stream>>>(
      tmp, bucket_off, pairs, row_start, n_nodes, n_edges);

  // GEMM after pass D: sup overwrites the tmp region.
  gcn_gemm_kernel<<<dim3((n_nodes + 31) / 32), dim3(256), 0, stream>>>(
      x, W, b, sup, n_nodes);

  int gblocks = ((n_nodes * 64) + 255) / 256;
  gather_kernel<<<dim3(gblocks), dim3(256), 0, stream>>>(
      (const unsigned*)sup, row_start, pairs, out, n_nodes);
}

// Round 4
// 308.918 us; speedup vs baseline: 9.2893x; 1.2663x over previous
//
#include <hip/hip_runtime.h>

#define D 128
#define D4 32        // D/4 float4 groups
#define NB_MAX 512   // max coarse buckets (n_nodes/256 = 391 here)
#define CH 2048      // edges per partition block

__device__ inline unsigned short f2bf(float f) {
  unsigned u = __float_as_uint(f);
  u += 0x7fffu + ((u >> 16) & 1u);   // round-to-nearest-even
  return (unsigned short)(u >> 16);
}

// ---------------------------------------------------------------------------
// GEMM: support[n][c] = b[c] + sum_k x[n][k]*W[k][c], output stored as bf16.
// ---------------------------------------------------------------------------
__global__ __launch_bounds__(256) void gcn_gemm_kernel(
    const float* __restrict__ x, const float* __restrict__ W,
    const float* __restrict__ b, unsigned short* __restrict__ sup, int n_nodes) {
  __shared__ float Ws[D * D];    // 64 KB
  __shared__ float xs[32 * D];   // 16 KB
  const int t = threadIdx.x;
  const int node0 = blockIdx.x * 32;

  const float4* W4 = (const float4*)W;
  float4* Ws4 = (float4*)Ws;
#pragma unroll
  for (int i = 0; i < 16; ++i) Ws4[t + 256 * i] = W4[t + 256 * i];

  const float4* x4 = (const float4*)x;
  float4* xs4 = (float4*)xs;
#pragma unroll
  for (int i = 0; i < 4; ++i) {
    int l = t + 256 * i;
    int r = l >> 5, k4 = l & 31;
    int node = node0 + r;
    float4 v = make_float4(0.f, 0.f, 0.f, 0.f);
    if (node < n_nodes) v = x4[(size_t)node * D4 + k4];
    xs4[l] = v;
  }
  __syncthreads();

  const int cg = t & 31;
  const int r0 = (t >> 5) * 4;

  float4 bv = ((const float4*)b)[cg];
  float4 acc[4];
#pragma unroll
  for (int r = 0; r < 4; ++r) acc[r] = bv;

  for (int k = 0; k < D; k += 4) {
    float4 wv[4];
#pragma unroll
    for (int j = 0; j < 4; ++j) wv[j] = Ws4[(k + j) * D4 + cg];
    float4 xv[4];
#pragma unroll
    for (int r = 0; r < 4; ++r) xv[r] = xs4[(r0 + r) * D4 + (k >> 2)];
#pragma unroll
    for (int r = 0; r < 4; ++r) {
      float xr;
      xr = xv[r].x;
      acc[r].x += xr * wv[0].x; acc[r].y += xr * wv[0].y;
      acc[r].z += xr * wv[0].z; acc[r].w += xr * wv[0].w;
      xr = xv[r].y;
      acc[r].x += xr * wv[1].x; acc[r].y += xr * wv[1].y;
      acc[r].z += xr * wv[1].z; acc[r].w += xr * wv[1].w;
      xr = xv[r].z;
      acc[r].x += xr * wv[2].x; acc[r].y += xr * wv[2].y;
      acc[r].z += xr * wv[2].z; acc[r].w += xr * wv[2].w;
      xr = xv[r].w;
      acc[r].x += xr * wv[3].x; acc[r].y += xr * wv[3].y;
      acc[r].z += xr * wv[3].z; acc[r].w += xr * wv[3].w;
    }
  }

  ushort4* sup4 = (ushort4*)sup;
#pragma unroll
  for (int r = 0; r < 4; ++r) {
    int node = node0 + r0 + r;
    if (node < n_nodes) {
      ushort4 o;
      o.x = f2bf(acc[r].x); o.y = f2bf(acc[r].y);
      o.z = f2bf(acc[r].z); o.w = f2bf(acc[r].w);
      sup4[(size_t)node * D4 + cg] = o;
    }
  }
}

// ---------------------------------------------------------------------------
// Pass A: coarse bucket histogram (bucket = row >> 8), LDS-privatized.
// ---------------------------------------------------------------------------
__global__ __launch_bounds__(256) void bucket_hist_kernel(
    const int* __restrict__ rows, int* __restrict__ bucket_cnt, int n_edges) {
  __shared__ int h[NB_MAX];
  int t = threadIdx.x;
  for (int i = t; i < NB_MAX; i += 256) h[i] = 0;
  __syncthreads();
  int lo = blockIdx.x * 4096;
  int hi = min(lo + 4096, n_edges);
  for (int i = lo + t; i < hi; i += 256) atomicAdd(&h[rows[i] >> 8], 1);
  __syncthreads();
  for (int i = t; i < NB_MAX; i += 256)
    if (h[i]) atomicAdd(&bucket_cnt[i], h[i]);
}

// ---------------------------------------------------------------------------
// Pass B: scan bucket counts -> bucket_off, init bucket_cursor. One block.
// ---------------------------------------------------------------------------
__global__ __launch_bounds__(512) void bucket_scan_kernel(
    const int* __restrict__ bucket_cnt, int* __restrict__ bucket_off,
    int* __restrict__ bucket_cursor, int nb) {
  __shared__ int s[512];
  int t = threadIdx.x;
  s[t] = (t < nb) ? bucket_cnt[t] : 0;
  __syncthreads();
  for (int d = 1; d < 512; d <<= 1) {
    int v = (t >= d) ? s[t - d] : 0;
    __syncthreads();
    s[t] += v;
    __syncthreads();
  }
  int excl = (t == 0) ? 0 : s[t - 1];
  if (t < nb) { bucket_off[t] = excl; bucket_cursor[t] = excl; }
  if (t == nb) bucket_off[t] = s[nb - 1];   // total = n_edges
}

// ---------------------------------------------------------------------------
// Pass C: partition edges into bucket-contiguous regions of tmp.
// ---------------------------------------------------------------------------
__global__ __launch_bounds__(256) void partition_kernel(
    const int* __restrict__ rows, const int* __restrict__ cols,
    const float* __restrict__ vals, int* __restrict__ bucket_cursor,
    int2* __restrict__ tmp, int n_edges) {
  __shared__ int h[NB_MAX];
  __shared__ int base_s[NB_MAX];
  int t = threadIdx.x;
  for (int i = t; i < NB_MAX; i += 256) h[i] = 0;
  __syncthreads();
  int lo = blockIdx.x * CH;
  int hi = min(lo + CH, n_edges);
  for (int i = lo + t; i < hi; i += 256) atomicAdd(&h[rows[i] >> 8], 1);
  __syncthreads();
  for (int i = t; i < NB_MAX; i += 256) {
    int c = h[i];
    base_s[i] = c ? atomicAdd(&bucket_cursor[i], c) : 0;
    h[i] = 0;   // reuse as local cursor
  }
  __syncthreads();
  for (int i = lo + t; i < hi; i += 256) {
    int r = rows[i];
    int bkt = r >> 8;
    int l = atomicAdd(&h[bkt], 1);
    int pos = base_s[bkt] + l;
    tmp[pos] = make_int2(((r & 255) << 17) | cols[i], __float_as_int(vals[i]));
  }
}

// ---------------------------------------------------------------------------
// Pass D: per-bucket counting sort (256 local rows) -> final CSR pairs +
// row_start. One block per bucket; scatter confined to the bucket's ~32 KB.
// ---------------------------------------------------------------------------
__global__ __launch_bounds__(256) void bucket_sort_kernel(
    const int2* __restrict__ tmp, const int* __restrict__ bucket_off,
    int2* __restrict__ pairs, int* __restrict__ row_start,
    int n_nodes, int n_edges) {
  __shared__ int cnt[256];
  __shared__ int loff[256];
  __shared__ int s[256];
  int b = blockIdx.x, t = threadIdx.x;
  cnt[t] = 0;
  __syncthreads();
  int lo = bucket_off[b], hi = bucket_off[b + 1];
  for (int i = lo + t; i < hi; i += 256) {
    int lr = ((unsigned)tmp[i].x) >> 17;
    atomicAdd(&cnt[lr], 1);
  }
  __syncthreads();
  s[t] = cnt[t];
  __syncthreads();
  for (int d = 1; d < 256; d <<= 1) {
    int v = (t >= d) ? s[t - d] : 0;
    __syncthreads();
    s[t] += v;
    __syncthreads();
  }
  int excl = (t == 0) ? 0 : s[t - 1];
  loff[t] = excl;
  cnt[t] = 0;   // reuse as per-row cursor
  int g = (b << 8) + t;
  if (g < n_nodes) row_start[g] = lo + excl;
  if (b == 0 && t == 0) row_start[n_nodes] = n_edges;
  __syncthreads();
  for (int i = lo + t; i < hi; i += 256) {
    int2 p = tmp[i];
    int lr = ((unsigned)p.x) >> 17;
    int l = atomicAdd(&cnt[lr], 1);
    pairs[lo + loff[lr] + l] = make_int2(p.x & 0x1FFFF, p.y);
  }
}

// ---------------------------------------------------------------------------
// Gather: 32 lanes per row (2 independent rows per wave), 4 bf16 per lane
// via uint2. Edge loop unrolled x4 -> 4 outstanding 256 B gathers per row
// stream (8 per wave) to fix the MLP bottleneck seen in round 3.
// ---------------------------------------------------------------------------
__global__ __launch_bounds__(256) void gather_kernel(
    const uint2* __restrict__ sup, const int* __restrict__ row_start,
    const int2* __restrict__ pairs, float* __restrict__ out, int n_nodes) {
  int tid = blockIdx.x * 256 + threadIdx.x;
  int g = tid >> 5;       // row
  int lane = tid & 31;    // uint2 slot (features lane*4 .. lane*4+3)
  if (g >= n_nodes) return;

  int s = row_start[g];
  int e = row_start[g + 1];

  float4 acc = make_float4(0.f, 0.f, 0.f, 0.f);
  int i = s;
  for (; i + 4 <= e; i += 4) {
    int2 p0 = pairs[i + 0];
    int2 p1 = pairs[i + 1];
    int2 p2 = pairs[i + 2];
    int2 p3 = pairs[i + 3];
    uint2 s0 = sup[((size_t)p0.x << 5) + lane];
    uint2 s1 = sup[((size_t)p1.x << 5) + lane];
    uint2 s2 = sup[((size_t)p2.x << 5) + lane];
    uint2 s3 = sup[((size_t)p3.x << 5) + lane];
    float v0 = __int_as_float(p0.y), v1 = __int_as_float(p1.y);
    float v2 = __int_as_float(p2.y), v3 = __int_as_float(p3.y);
    acc.x += v0 * __uint_as_float(s0.x << 16);
    acc.y += v0 * __uint_as_float(s0.x & 0xffff0000u);
    acc.z += v0 * __uint_as_float(s0.y << 16);
    acc.w += v0 * __uint_as_float(s0.y & 0xffff0000u);
    acc.x += v1 * __uint_as_float(s1.x << 16);
    acc.y += v1 * __uint_as_float(s1.x & 0xffff0000u);
    acc.z += v1 * __uint_as_float(s1.y << 16);
    acc.w += v1 * __uint_as_float(s1.y & 0xffff0000u);
    acc.x += v2 * __uint_as_float(s2.x << 16);
    acc.y += v2 * __uint_as_float(s2.x & 0xffff0000u);
    acc.z += v2 * __uint_as_float(s2.y << 16);
    acc.w += v2 * __uint_as_float(s2.y & 0xffff0000u);
    acc.x += v3 * __uint_as_float(s3.x << 16);
    acc.y += v3 * __uint_as_float(s3.x & 0xffff0000u);
    acc.z += v3 * __uint_as_float(s3.y << 16);
    acc.w += v3 * __uint_as_float(s3.y & 0xffff0000u);
  }
  for (; i < e; ++i) {
    int2 p = pairs[i];
    float val = __int_as_float(p.y);
    uint2 sv = sup[((size_t)p.x << 5) + lane];
    acc.x += val * __uint_as_float(sv.x << 16);
    acc.y += val * __uint_as_float(sv.x & 0xffff0000u);
    acc.z += val * __uint_as_float(sv.y << 16);
    acc.w += val * __uint_as_float(sv.y & 0xffff0000u);
  }
  ((float4*)out)[((size_t)g << 5) + lane] = acc;
}

extern "C" void kernel_launch(void* const* d_in, const int* in_sizes, int n_in,
                              void* d_out, int out_size, void* d_ws, size_t ws_size,
                              hipStream_t stream) {
  const float* x    = (const float*)d_in[0];
  const int*   rows = (const int*)d_in[1];
  const int*   cols = (const int*)d_in[2];
  const float* vals = (const float*)d_in[3];
  const float* W    = (const float*)d_in[4];
  const float* b    = (const float*)d_in[5];
  float* out = (float*)d_out;

  int n_nodes = in_sizes[0] / D;
  int n_edges = in_sizes[1];
  int nb = (n_nodes + 255) >> 8;   // 391 coarse buckets

  char* ws = (char*)d_ws;
  unsigned short* sup = (unsigned short*)(ws);
  int2* tmp           = (int2*)(ws);                 // dead once GEMM runs
  int2* pairs         = (int2*)(ws + 25600000);
  int* row_start      = (int*)(ws + 38400000);       // 400,004 B
  int* bucket_cnt     = (int*)(ws + 38800016);       // 1,568 B
  int* bucket_off     = (int*)(ws + 38801600);       // 1,568 B
  int* bucket_cursor  = (int*)(ws + 38803168);       // 1,568 B

  hipMemsetAsync(bucket_cnt, 0, (size_t)nb * sizeof(int), stream);

  int ablocks = (n_edges + 4095) / 4096;
  bucket_hist_kernel<<<dim3(ablocks), dim3(256), 0, stream>>>(
      rows, bucket_cnt, n_edges);
  bucket_scan_kernel<<<dim3(1), dim3(512), 0, stream>>>(
      bucket_cnt, bucket_off, bucket_cursor, nb);
  int cblocks = (n_edges + CH - 1) / CH;
  partition_kernel<<<dim3(cblocks), dim3(256), 0, stream>>>(
      rows, cols, vals, bucket_cursor, tmp, n_edges);
  bucket_sort_kernel<<<dim3(nb), dim3(256), 0, stream>>>(
      tmp, bucket_off, pairs, row_start, n_nodes, n_edges);

  // GEMM after pass D: sup overwrites the tmp region.
  gcn_gemm_kernel<<<dim3((n_nodes + 31) / 32), dim3(256), 0, stream>>>(
      x, W, b, sup, n_nodes);

  int gblocks = ((n_nodes * 32) + 255) / 256;
  gather_kernel<<<dim3(gblocks), dim3(256), 0, stream>>>(
      (const uint2*)sup, row_start, pairs, out, n_nodes);
}

// Round 5
// 275.213 us; speedup vs baseline: 10.4269x; 1.1225x over previous
//
#include <hip/hip_runtime.h>

#define D 128
#define NB_MAX 512   // max coarse buckets (n_nodes/256 = 391 here)
#define CH 2048      // edges per partition block
#define SP 136       // padded LDS row stride (bf16 elems) for x tile

typedef short short8 __attribute__((ext_vector_type(8)));
typedef float floatx4 __attribute__((ext_vector_type(4)));

__device__ inline unsigned short f2bf(float f) {
  unsigned u = __float_as_uint(f);
  u += 0x7fffu + ((u >> 16) & 1u);   // round-to-nearest-even
  return (unsigned short)(u >> 16);
}

// ---------------------------------------------------------------------------
// One-off: pre-swizzle W (128x128 fp32) into MFMA B-fragment order, bf16.
// wf[ks][nt][lane][j] = W[ks*32 + (lane>>4)*8 + j][nt*16 + (lane&15)]
// ---------------------------------------------------------------------------
__global__ __launch_bounds__(256) void wf_pack_kernel(
    const float* __restrict__ W, unsigned short* __restrict__ wf) {
  int tid = blockIdx.x * 256 + threadIdx.x;   // 0..2047
  int ks = tid >> 9;
  int rem = tid & 511;
  int nt = rem >> 6;
  int lane = rem & 63;
  int n = nt * 16 + (lane & 15);
  int k0 = ks * 32 + (lane >> 4) * 8;
  unsigned short v[8];
#pragma unroll
  for (int j = 0; j < 8; ++j) v[j] = f2bf(W[(k0 + j) * D + n]);
  uint4 o;
  o.x = (unsigned)v[0] | ((unsigned)v[1] << 16);
  o.y = (unsigned)v[2] | ((unsigned)v[3] << 16);
  o.z = (unsigned)v[4] | ((unsigned)v[5] << 16);
  o.w = (unsigned)v[6] | ((unsigned)v[7] << 16);
  ((uint4*)wf)[tid] = o;
}

// ---------------------------------------------------------------------------
// MFMA GEMM: support[n][c] = b[c] + sum_k x[n][k]*W[k][c], stored bf16.
// Block = 64 nodes x 128 cols, 4 waves in 2x2 (wave = 32 rows x 64 cols).
// 16x16x32 bf16 MFMA; per kstep per wave: 2 A-frags + 4 B-frags -> 8 MFMA.
// LDS: wf fragments 32 KB + padded x tile 17 KB = 49 KB -> 3 blocks/CU.
// ---------------------------------------------------------------------------
__global__ __launch_bounds__(256) void gcn_gemm_mfma_kernel(
    const float* __restrict__ x, const unsigned short* __restrict__ wf,
    const float* __restrict__ b, unsigned short* __restrict__ sup, int n_nodes) {
  __shared__ unsigned short xs[64 * SP];   // 17,408 B
  __shared__ unsigned short wfs[16384];    // 32,768 B
  const int t = threadIdx.x;
  const int node0 = blockIdx.x * 64;
  const int lane = t & 63;
  const int w = t >> 6;

  // stage wf -> LDS (contiguous 32 KB)
  const uint4* wf4 = (const uint4*)wf;
  uint4* wfs4 = (uint4*)wfs;
#pragma unroll
  for (int i = 0; i < 8; ++i) wfs4[t + 256 * i] = wf4[t + 256 * i];

  // stage x tile (64 x 128 fp32) -> bf16 LDS (row stride SP, zero-padded rows)
  const float4* x4 = (const float4*)x;
#pragma unroll
  for (int i = 0; i < 8; ++i) {
    int idx = t + 256 * i;       // 0..2047
    int row = idx >> 5, k4 = idx & 31;
    int node = node0 + row;
    float4 v = make_float4(0.f, 0.f, 0.f, 0.f);
    if (node < n_nodes) v = x4[(size_t)node * 32 + k4];
    unsigned u0 = (unsigned)f2bf(v.x) | ((unsigned)f2bf(v.y) << 16);
    unsigned u1 = (unsigned)f2bf(v.z) | ((unsigned)f2bf(v.w) << 16);
    *((uint2*)(xs + row * SP + k4 * 4)) = make_uint2(u0, u1);
  }
  __syncthreads();

  const int rb = (w & 1) * 32;    // wave row base
  const int cb = (w >> 1) * 64;   // wave col base
  const int m = lane & 15, q = lane >> 4;

  floatx4 acc[2][4];
#pragma unroll
  for (int ct = 0; ct < 4; ++ct) {
    float bv = b[cb + ct * 16 + m];
#pragma unroll
    for (int rt = 0; rt < 2; ++rt) {
      acc[rt][ct][0] = bv; acc[rt][ct][1] = bv;
      acc[rt][ct][2] = bv; acc[rt][ct][3] = bv;
    }
  }

#pragma unroll
  for (int ks = 0; ks < 4; ++ks) {
    short8 af[2], bfr[4];
#pragma unroll
    for (int rt = 0; rt < 2; ++rt)
      af[rt] = *((const short8*)(xs + (rb + rt * 16 + m) * SP + ks * 32 + q * 8));
#pragma unroll
    for (int ct = 0; ct < 4; ++ct) {
      int nt = (cb >> 4) + ct;
      bfr[ct] = *((const short8*)(wfs + ((ks * 8 + nt) * 64 + lane) * 8));
    }
#pragma unroll
    for (int rt = 0; rt < 2; ++rt)
#pragma unroll
      for (int ct = 0; ct < 4; ++ct)
        acc[rt][ct] = __builtin_amdgcn_mfma_f32_16x16x32_bf16(
            af[rt], bfr[ct], acc[rt][ct], 0, 0, 0);
  }

  __syncthreads();
  // acc -> LDS bf16 [row][col] (stride SP), C/D map: row=(lane>>4)*4+r, col=m
#pragma unroll
  for (int rt = 0; rt < 2; ++rt)
#pragma unroll
    for (int ct = 0; ct < 4; ++ct)
#pragma unroll
      for (int r = 0; r < 4; ++r) {
        int row = rb + rt * 16 + q * 4 + r;
        int col = cb + ct * 16 + m;
        xs[row * SP + col] = f2bf(acc[rt][ct][r]);
      }
  __syncthreads();

  // coalesced copy out (16 B per thread-iter)
  uint4* sup4 = (uint4*)sup;
#pragma unroll
  for (int i = 0; i < 4; ++i) {
    int idx = t + 256 * i;     // 0..1023
    int row = idx >> 4, ch = idx & 15;
    int node = node0 + row;
    if (node < n_nodes)
      sup4[(size_t)node * 16 + ch] = *((const uint4*)(xs + row * SP + ch * 8));
  }
}

// ---------------------------------------------------------------------------
// Pass A: coarse bucket histogram (bucket = row >> 8), LDS-privatized.
// ---------------------------------------------------------------------------
__global__ __launch_bounds__(256) void bucket_hist_kernel(
    const int* __restrict__ rows, int* __restrict__ bucket_cnt, int n_edges) {
  __shared__ int h[NB_MAX];
  int t = threadIdx.x;
  for (int i = t; i < NB_MAX; i += 256) h[i] = 0;
  __syncthreads();
  int lo = blockIdx.x * 4096;
  int hi = min(lo + 4096, n_edges);
  for (int i = lo + t; i < hi; i += 256) atomicAdd(&h[rows[i] >> 8], 1);
  __syncthreads();
  for (int i = t; i < NB_MAX; i += 256)
    if (h[i]) atomicAdd(&bucket_cnt[i], h[i]);
}

// ---------------------------------------------------------------------------
// Pass B: scan bucket counts -> bucket_off, init bucket_cursor. One block.
// ---------------------------------------------------------------------------
__global__ __launch_bounds__(512) void bucket_scan_kernel(
    const int* __restrict__ bucket_cnt, int* __restrict__ bucket_off,
    int* __restrict__ bucket_cursor, int nb) {
  __shared__ int s[512];
  int t = threadIdx.x;
  s[t] = (t < nb) ? bucket_cnt[t] : 0;
  __syncthreads();
  for (int d = 1; d < 512; d <<= 1) {
    int v = (t >= d) ? s[t - d] : 0;
    __syncthreads();
    s[t] += v;
    __syncthreads();
  }
  int excl = (t == 0) ? 0 : s[t - 1];
  if (t < nb) { bucket_off[t] = excl; bucket_cursor[t] = excl; }
  if (t == nb) bucket_off[t] = s[nb - 1];   // total = n_edges
}

// ---------------------------------------------------------------------------
// Pass C: partition edges into bucket-contiguous regions of tmp.
// ---------------------------------------------------------------------------
__global__ __launch_bounds__(256) void partition_kernel(
    const int* __restrict__ rows, const int* __restrict__ cols,
    const float* __restrict__ vals, int* __restrict__ bucket_cursor,
    int2* __restrict__ tmp, int n_edges) {
  __shared__ int h[NB_MAX];
  __shared__ int base_s[NB_MAX];
  int t = threadIdx.x;
  for (int i = t; i < NB_MAX; i += 256) h[i] = 0;
  __syncthreads();
  int lo = blockIdx.x * CH;
  int hi = min(lo + CH, n_edges);
  for (int i = lo + t; i < hi; i += 256) atomicAdd(&h[rows[i] >> 8], 1);
  __syncthreads();
  for (int i = t; i < NB_MAX; i += 256) {
    int c = h[i];
    base_s[i] = c ? atomicAdd(&bucket_cursor[i], c) : 0;
    h[i] = 0;   // reuse as local cursor
  }
  __syncthreads();
  for (int i = lo + t; i < hi; i += 256) {
    int r = rows[i];
    int bkt = r >> 8;
    int l = atomicAdd(&h[bkt], 1);
    int pos = base_s[bkt] + l;
    tmp[pos] = make_int2(((r & 255) << 17) | cols[i], __float_as_int(vals[i]));
  }
}

// ---------------------------------------------------------------------------
// Pass D: per-bucket counting sort (256 local rows) -> final CSR pairs +
// row_start. One block per bucket; scatter confined to the bucket's ~32 KB.
// ---------------------------------------------------------------------------
__global__ __launch_bounds__(256) void bucket_sort_kernel(
    const int2* __restrict__ tmp, const int* __restrict__ bucket_off,
    int2* __restrict__ pairs, int* __restrict__ row_start,
    int n_nodes, int n_edges) {
  __shared__ int cnt[256];
  __shared__ int loff[256];
  __shared__ int s[256];
  int b = blockIdx.x, t = threadIdx.x;
  cnt[t] = 0;
  __syncthreads();
  int lo = bucket_off[b], hi = bucket_off[b + 1];
  for (int i = lo + t; i < hi; i += 256) {
    int lr = ((unsigned)tmp[i].x) >> 17;
    atomicAdd(&cnt[lr], 1);
  }
  __syncthreads();
  s[t] = cnt[t];
  __syncthreads();
  for (int d = 1; d < 256; d <<= 1) {
    int v = (t >= d) ? s[t - d] : 0;
    __syncthreads();
    s[t] += v;
    __syncthreads();
  }
  int excl = (t == 0) ? 0 : s[t - 1];
  loff[t] = excl;
  cnt[t] = 0;   // reuse as per-row cursor
  int g = (b << 8) + t;
  if (g < n_nodes) row_start[g] = lo + excl;
  if (b == 0 && t == 0) row_start[n_nodes] = n_edges;
  __syncthreads();
  for (int i = lo + t; i < hi; i += 256) {
    int2 p = tmp[i];
    int lr = ((unsigned)p.x) >> 17;
    int l = atomicAdd(&cnt[lr], 1);
    pairs[lo + loff[lr] + l] = make_int2(p.x & 0x1FFFF, p.y);
  }
}

// ---------------------------------------------------------------------------
// Gather: 32 lanes per row (2 independent rows per wave), 4 bf16 per lane
// via uint2; edge loop unrolled x4 -> 8 outstanding gathers per wave.
// ---------------------------------------------------------------------------
__global__ __launch_bounds__(256) void gather_kernel(
    const uint2* __restrict__ sup, const int* __restrict__ row_start,
    const int2* __restrict__ pairs, float* __restrict__ out, int n_nodes) {
  int tid = blockIdx.x * 256 + threadIdx.x;
  int g = tid >> 5;       // row
  int lane = tid & 31;    // uint2 slot (features lane*4 .. lane*4+3)
  if (g >= n_nodes) return;

  int s = row_start[g];
  int e = row_start[g + 1];

  float4 acc = make_float4(0.f, 0.f, 0.f, 0.f);
  int i = s;
  for (; i + 4 <= e; i += 4) {
    int2 p0 = pairs[i + 0];
    int2 p1 = pairs[i + 1];
    int2 p2 = pairs[i + 2];
    int2 p3 = pairs[i + 3];
    uint2 s0 = sup[((size_t)p0.x << 5) + lane];
    uint2 s1 = sup[((size_t)p1.x << 5) + lane];
    uint2 s2 = sup[((size_t)p2.x << 5) + lane];
    uint2 s3 = sup[((size_t)p3.x << 5) + lane];
    float v0 = __int_as_float(p0.y), v1 = __int_as_float(p1.y);
    float v2 = __int_as_float(p2.y), v3 = __int_as_float(p3.y);
    acc.x += v0 * __uint_as_float(s0.x << 16);
    acc.y += v0 * __uint_as_float(s0.x & 0xffff0000u);
    acc.z += v0 * __uint_as_float(s0.y << 16);
    acc.w += v0 * __uint_as_float(s0.y & 0xffff0000u);
    acc.x += v1 * __uint_as_float(s1.x << 16);
    acc.y += v1 * __uint_as_float(s1.x & 0xffff0000u);
    acc.z += v1 * __uint_as_float(s1.y << 16);
    acc.w += v1 * __uint_as_float(s1.y & 0xffff0000u);
    acc.x += v2 * __uint_as_float(s2.x << 16);
    acc.y += v2 * __uint_as_float(s2.x & 0xffff0000u);
    acc.z += v2 * __uint_as_float(s2.y << 16);
    acc.w += v2 * __uint_as_float(s2.y & 0xffff0000u);
    acc.x += v3 * __uint_as_float(s3.x << 16);
    acc.y += v3 * __uint_as_float(s3.x & 0xffff0000u);
    acc.z += v3 * __uint_as_float(s3.y << 16);
    acc.w += v3 * __uint_as_float(s3.y & 0xffff0000u);
  }
  for (; i < e; ++i) {
    int2 p = pairs[i];
    float val = __int_as_float(p.y);
    uint2 sv = sup[((size_t)p.x << 5) + lane];
    acc.x += val * __uint_as_float(sv.x << 16);
    acc.y += val * __uint_as_float(sv.x & 0xffff0000u);
    acc.z += val * __uint_as_float(sv.y << 16);
    acc.w += val * __uint_as_float(sv.y & 0xffff0000u);
  }
  ((float4*)out)[((size_t)g << 5) + lane] = acc;
}

extern "C" void kernel_launch(void* const* d_in, const int* in_sizes, int n_in,
                              void* d_out, int out_size, void* d_ws, size_t ws_size,
                              hipStream_t stream) {
  const float* x    = (const float*)d_in[0];
  const int*   rows = (const int*)d_in[1];
  const int*   cols = (const int*)d_in[2];
  const float* vals = (const float*)d_in[3];
  const float* W    = (const float*)d_in[4];
  const float* b    = (const float*)d_in[5];
  float* out = (float*)d_out;

  int n_nodes = in_sizes[0] / D;
  int n_edges = in_sizes[1];
  int nb = (n_nodes + 255) >> 8;   // 391 coarse buckets

  char* ws = (char*)d_ws;
  unsigned short* sup = (unsigned short*)(ws);
  int2* tmp           = (int2*)(ws);                 // dead once GEMM runs
  int2* pairs         = (int2*)(ws + 25600000);
  int* row_start      = (int*)(ws + 38400000);       // 400,004 B
  int* bucket_cnt     = (int*)(ws + 38800016);       // 1,568 B
  int* bucket_off     = (int*)(ws + 38801600);       // 1,568 B
  int* bucket_cursor  = (int*)(ws + 38803168);       // 1,568 B
  unsigned short* wf  = (unsigned short*)(ws + 38804736);  // 32,768 B

  hipMemsetAsync(bucket_cnt, 0, (size_t)nb * sizeof(int), stream);

  wf_pack_kernel<<<dim3(8), dim3(256), 0, stream>>>(W, wf);

  int ablocks = (n_edges + 4095) / 4096;
  bucket_hist_kernel<<<dim3(ablocks), dim3(256), 0, stream>>>(
      rows, bucket_cnt, n_edges);
  bucket_scan_kernel<<<dim3(1), dim3(512), 0, stream>>>(
      bucket_cnt, bucket_off, bucket_cursor, nb);
  int cblocks = (n_edges + CH - 1) / CH;
  partition_kernel<<<dim3(cblocks), dim3(256), 0, stream>>>(
      rows, cols, vals, bucket_cursor, tmp, n_edges);
  bucket_sort_kernel<<<dim3(nb), dim3(256), 0, stream>>>(
      tmp, bucket_off, pairs, row_start, n_nodes, n_edges);

  // GEMM after pass D: sup overwrites the tmp region.
  gcn_gemm_mfma_kernel<<<dim3((n_nodes + 63) / 64), dim3(256), 0, stream>>>(
      x, wf, b, sup, n_nodes);

  int gblocks = ((n_nodes * 32) + 255) / 256;
  gather_kernel<<<dim3(gblocks), dim3(256), 0, stream>>>(
      (const uint2*)sup, row_start, pairs, out, n_nodes);
}